// Round 2
// baseline (2216.182 us; speedup 1.0000x reference)
//
#include <hip/hip_runtime.h>
#include <cstdint>
#include <cstddef>

typedef _Float16 half_t;
typedef _Float16 half8 __attribute__((ext_vector_type(8)));
typedef float f32x4 __attribute__((ext_vector_type(4)));

constexpr int NN = 131072;    // nodes
constexpr int NE = 1048576;   // edges
constexpr int NPER = 512;

#define DEVINL __device__ __forceinline__

DEVINL float sigm_(float x){ return 1.f/(1.f+__expf(-x)); }
DEVINL float tanh_(float x){
  x = fminf(15.f, fmaxf(-15.f, x));
  float e = __expf(-2.f*x);
  return (1.f-e)/(1.f+e);
}

// ---------------- tiny precompute kernels ----------------

__global__ void const_kernel(const float* __restrict__ gatW, const float* __restrict__ attS,
                             const float* __restrict__ attD, const float* __restrict__ gatWe,
                             const float* __restrict__ attE, const float* __restrict__ eW,
                             const float* __restrict__ eb,
                             float* __restrict__ vs, float* __restrict__ vd, float* __restrict__ cc){
  int l = blockIdx.x, k = threadIdx.x;   // 3 blocks x 64 threads
  const float* Wl = gatW + l*4096;
  const float* Wel = gatWe + l*4096;
  float s1=0.f,s2=0.f,s3=0.f;
  for (int j=0;j<64;j++){
    float as = attS[l*64+j], ad = attD[l*64+j], ae = attE[l*64+j];
    s1 += Wl[k*64+j]*as;
    s2 += Wl[k*64+j]*ad;
    s3 += Wel[k*64+j]*ae;
  }
  vs[l*64+k]=s1; vd[l*64+k]=s2;
  float c0 = eW[k]*s3, c1 = eW[64+k]*s3, cb = eb[k]*s3;
  for (int off=1; off<64; off<<=1){
    c0 += __shfl_xor(c0,off); c1 += __shfl_xor(c1,off); cb += __shfl_xor(cb,off);
  }
  if (k==0){ cc[l]=c0; cc[3+l]=c1; cc[6+l]=cb; }
}

// pack/transpose weights to f16
__global__ void prep_pack(const float* __restrict__ wih_f, const float* __restrict__ wih_b,
                          const float* __restrict__ head_W1, const float* __restrict__ gat_W,
                          const float* __restrict__ bih_f, const float* __restrict__ bih_b,
                          half_t* __restrict__ BcombT, half_t* __restrict__ W1T,
                          half_t* __restrict__ BTgat, float* __restrict__ bias_comb){
  int gid = blockIdx.x*256 + threadIdx.x;
  if (gid < 147456){                       // BcombT: j<384 from wih_f else wih_b, k-contig
    int j = gid/192, k = gid%192;
    float v = (j<384)? wih_f[j*192+k] : wih_b[(j-384)*192+k];
    BcombT[gid] = (half_t)v;
  } else if (gid < 163840){                // W1T[n][k] = head_W1[k][n]
    int i = gid - 147456;
    int n = i>>8, k = i&255;
    W1T[i] = (half_t)head_W1[k*64+n];
  } else if (gid < 176128){                // BTgat[l][n][k] = gat_W[l][k][n]
    int i = gid - 163840;
    int l = i>>12, r = i&4095;
    int n = r>>6, k = r&63;
    BTgat[i] = (half_t)gat_W[l*4096 + k*64 + n];
  } else if (gid < 176896){
    int i = gid - 176128;
    bias_comb[i] = (i<384)? bih_f[i] : bih_b[i-384];
  }
}

// ---------------- node embedding ----------------
__global__ __launch_bounds__(256) void embed_kernel(const float* __restrict__ x,
                            const float* __restrict__ nW, const float* __restrict__ nb,
                            half_t* __restrict__ h){
  int gid = blockIdx.x*256 + threadIdx.x;
  int n = gid>>6, j = gid&63;
  float v = x[2*n]*nW[j] + x[2*n+1]*nW[64+j] + nb[j];
  h[(size_t)n*64+j] = (half_t)v;
}

// ---------------- edge preprocessing ----------------
__global__ __launch_bounds__(256) void edge_pre(const int* __restrict__ ei, const float* __restrict__ ea,
                         const float* __restrict__ cc,
                         float* __restrict__ a_e, float* __restrict__ aloop, int* __restrict__ deg){
  int e = blockIdx.x*256 + threadIdx.x;
  int dt = ei[NE+e];
  float e0 = ea[2*e], e1 = ea[2*e+1];
  atomicAdd(&deg[dt],1);
  #pragma unroll
  for (int l=0;l<3;l++){
    float v = e0*cc[l] + e1*cc[3+l] + cc[6+l];
    a_e[(size_t)l*NE+e] = v;
    atomicAdd(&aloop[(size_t)l*NN+dt], v);
  }
}

__global__ __launch_bounds__(256) void scan1(const int* __restrict__ deg, int* __restrict__ rowstart,
                      int* __restrict__ bsum){
  __shared__ int sc[256];
  int b=blockIdx.x, t=threadIdx.x, i=b*256+t;
  int v=deg[i]; sc[t]=v; __syncthreads();
  for (int off=1; off<256; off<<=1){
    int tv = (t>=off)? sc[t-off] : 0;
    __syncthreads(); sc[t]+=tv; __syncthreads();
  }
  rowstart[i]=sc[t]-v;
  if (t==255) bsum[b]=sc[255];
}
__global__ void scan2(int* __restrict__ bsum){   // 1 block x 512
  __shared__ int sc[512];
  int t=threadIdx.x; int v=bsum[t]; sc[t]=v; __syncthreads();
  for (int off=1; off<512; off<<=1){
    int tv = (t>=off)? sc[t-off] : 0;
    __syncthreads(); sc[t]+=tv; __syncthreads();
  }
  bsum[t]=sc[t]-v;
}
__global__ __launch_bounds__(256) void scan3(int* __restrict__ rowstart, const int* __restrict__ bsum,
                      const int* __restrict__ deg, float* __restrict__ aloop){
  int b=blockIdx.x, t=threadIdx.x, i=b*256+t;
  rowstart[i]+=bsum[b];
  float dv = (float)max(deg[i],1);
  aloop[i] /= dv; aloop[NN+i] /= dv; aloop[2*(size_t)NN+i] /= dv;
}

__global__ __launch_bounds__(256) void fill_csr(const int* __restrict__ ei, const int* __restrict__ rowstart,
                         int* __restrict__ cursor, int* __restrict__ csr_eid){
  int e = blockIdx.x*256 + threadIdx.x;
  int dt = ei[NE+e];
  int p = atomicAdd(&cursor[dt],1);
  csr_eid[rowstart[dt]+p] = e;
}

// ---------------- GAT per-layer kernels ----------------
__global__ __launch_bounds__(256) void attn_kernel(const half_t* __restrict__ h, const float* __restrict__ vs,
                            const float* __restrict__ vd, const float* __restrict__ aloop,
                            float* __restrict__ a_s, float* __restrict__ a_d, float* __restrict__ exs){
  int n = (blockIdx.x<<2) + (threadIdx.x>>6);
  int lane = threadIdx.x&63;
  float hv = (float)h[(size_t)n*64+lane];
  float ps = hv*vs[lane], pd = hv*vd[lane];
  for (int off=1; off<64; off<<=1){ ps += __shfl_xor(ps,off); pd += __shfl_xor(pd,off); }
  if (lane==0){
    a_s[n]=ps; a_d[n]=pd;
    float al = ps+pd+aloop[n];
    al = al>0.f? al : 0.2f*al;
    exs[n] = __expf(al);
  }
}

__global__ __launch_bounds__(256) void edge_soft(const int* __restrict__ ei, const float* __restrict__ a_s,
                          const float* __restrict__ a_d, const float* __restrict__ a_e,
                          float* __restrict__ ex, float* __restrict__ den){
  int e = blockIdx.x*256 + threadIdx.x;
  int s = ei[e], dt = ei[NE+e];
  float al = a_s[s] + a_d[dt] + a_e[e];
  al = al>0.f? al : 0.2f*al;
  float xv = __expf(al);
  ex[e]=xv;
  atomicAdd(&den[dt], xv);
}

__global__ __launch_bounds__(256) void agg_kernel(const int* __restrict__ ei, const int* __restrict__ rowstart,
                           const int* __restrict__ deg, const int* __restrict__ csr_eid,
                           const float* __restrict__ ex, const float* __restrict__ exs,
                           const float* __restrict__ den, const half_t* __restrict__ xp,
                           const float* __restrict__ bias, half_t* __restrict__ hout,
                           half_t* __restrict__ hjk, int l){
  int n = (blockIdx.x<<2) + (threadIdx.x>>6);
  int lane = threadIdx.x&63;
  float acc = exs[n]*(float)xp[(size_t)n*64+lane];
  int st = rowstart[n], cnt = deg[n];
  for (int i=0;i<cnt;i++){
    int eid = csr_eid[st+i];
    int src = ei[eid];
    float wv = ex[eid];
    acc += wv*(float)xp[(size_t)src*64+lane];
  }
  float dent = den[n]+exs[n];
  float v = acc/dent + bias[lane];
  v = v>0.f? v : 0.01f*v;
  hout[(size_t)n*64+lane]=(half_t)v;
  hjk[(size_t)n*192 + l*64 + lane]=(half_t)v;
}

// ---------------- f16 MFMA GEMM: C[M,Nout] = A[M,K] @ BT[Nout,K]^T (+bias)(+relu) ----------------
template<int BN, bool BIAS, bool RELU>
__global__ __launch_bounds__(256) void gemm_f16(const half_t* __restrict__ A, const half_t* __restrict__ BT,
                         const float* __restrict__ bias, half_t* __restrict__ C,
                         int K, int Nout){
  __shared__ half_t As[128*32];
  __shared__ half_t Bs[BN*32];
  const int tid = threadIdx.x;
  const int m0 = blockIdx.x * 128;
  const int n0 = blockIdx.y * BN;
  const int w = tid>>6, lane = tid&63;
  const int lm = lane&15, quad = lane>>4;
  const int wm0 = (BN==128)? (w>>1)*64 : w*32;
  const int wn0 = (BN==128)? (w&1)*64 : 0;
  constexpr int MT = (BN==128)?4:2;
  f32x4 acc[MT][4] = {};
  for (int k0=0; k0<K; k0+=32){
    {
      const int c0 = tid*2;
      #pragma unroll
      for (int u=0;u<2;u++){
        int c=c0+u; int row=c>>2; int off=(c&3)*8;
        *(half8*)(&As[row*32+off]) = *(const half8*)(&A[(size_t)(m0+row)*K + k0 + off]);
      }
      if (BN==128){
        #pragma unroll
        for (int u=0;u<2;u++){
          int c=c0+u; int row=c>>2; int off=(c&3)*8;
          *(half8*)(&Bs[row*32+off]) = *(const half8*)(&BT[(size_t)(n0+row)*K + k0 + off]);
        }
      } else {
        int c=tid; int row=c>>2; int off=(c&3)*8;
        *(half8*)(&Bs[row*32+off]) = *(const half8*)(&BT[(size_t)(n0+row)*K + k0 + off]);
      }
    }
    __syncthreads();
    half8 af[MT], bf[4];
    #pragma unroll
    for (int nt=0;nt<4;nt++) bf[nt] = *(const half8*)(&Bs[(wn0+nt*16+lm)*32 + quad*8]);
    #pragma unroll
    for (int mt=0;mt<MT;mt++) af[mt] = *(const half8*)(&As[(wm0+mt*16+lm)*32 + quad*8]);
    #pragma unroll
    for (int mt=0;mt<MT;mt++)
      #pragma unroll
      for (int nt=0;nt<4;nt++)
        acc[mt][nt] = __builtin_amdgcn_mfma_f32_16x16x32_f16(af[mt], bf[nt], acc[mt][nt], 0,0,0);
    __syncthreads();
  }
  #pragma unroll
  for (int mt=0;mt<MT;mt++)
   #pragma unroll
   for (int nt=0;nt<4;nt++)
    #pragma unroll
    for (int r=0;r<4;r++){
      int m = m0+wm0+mt*16+quad*4+r;
      int n = n0+wn0+nt*16+lm;
      float v = acc[mt][nt][r];
      if (BIAS) v += bias[n];
      if (RELU) v = v>0.f? v : 0.f;
      C[(size_t)m*Nout + n] = (half_t)v;
    }
}

// ---------------- GRU recurrence ----------------
// dirmode<0: blocks = 2*B_GRAPHS, bid&1 = direction, gx rows stride `gxstride`, dir offset 384.
// dirmode>=0: blocks = B_GRAPHS, direction fixed, gx offset 0.
__global__ __launch_bounds__(512) void gru_kernel(const float* __restrict__ whh_f, const float* __restrict__ whh_b,
                           const float* __restrict__ bhh_f, const float* __restrict__ bhh_b,
                           const half_t* __restrict__ gx, int gxstride, int dirmode,
                           half_t* __restrict__ y){
  const int bid = blockIdx.x;
  int g, d, gxoff;
  if (dirmode < 0){ g = bid>>1; d = bid&1; gxoff = d*384; }
  else           { g = bid;    d = dirmode; gxoff = 0; }
  const float* whh = d? whh_b : whh_f;
  const float* bhh = d? bhh_b : bhh_f;
  const int tid = threadIdx.x;
  const int q = tid>>2, sub = tid&3;
  float wreg[3][32];
  float bh[3];
  #pragma unroll
  for (int i=0;i<3;i++){
    int j = i*128+q;
    bh[i] = bhh[j];
    const float* wp = &whh[j*128 + sub*32];
    #pragma unroll
    for (int kk=0;kk<32;kk+=4)
      *(f32x4*)&wreg[i][kk] = *(const f32x4*)&wp[kk];
  }
  __shared__ float hbuf[2][128];
  if (tid<128) hbuf[0][tid]=0.f;
  __syncthreads();
  const size_t rowbase = (size_t)g*NPER;
  for (int s=0;s<NPER;s++){
    int rd = s&1, wr = rd^1;
    int pos = d? (NPER-1-s) : s;
    if (s>0 && tid<128){
      int ppos = d? (NPER-s) : (s-1);
      y[(rowbase+ppos)*256 + d*128 + tid] = (half_t)hbuf[rd][tid];
    }
    float p0=0.f,p1=0.f,p2=0.f;
    const float* hc = &hbuf[rd][sub*32];
    #pragma unroll
    for (int kk=0;kk<32;kk+=4){
      f32x4 h4 = *(const f32x4*)&hc[kk];
      #pragma unroll
      for (int m=0;m<4;m++){
        p0 += wreg[0][kk+m]*h4[m];
        p1 += wreg[1][kk+m]*h4[m];
        p2 += wreg[2][kk+m]*h4[m];
      }
    }
    p0 += __shfl_xor(p0,1); p0 += __shfl_xor(p0,2);
    p1 += __shfl_xor(p1,1); p1 += __shfl_xor(p1,2);
    p2 += __shfl_xor(p2,1); p2 += __shfl_xor(p2,2);
    const half_t* gxr = &gx[(size_t)(rowbase+pos)*gxstride + gxoff];
    float gr = (float)gxr[q], gz = (float)gxr[128+q], gn = (float)gxr[256+q];
    float r = sigm_(gr + p0 + bh[0]);
    float z = sigm_(gz + p1 + bh[1]);
    float nn = tanh_(gn + r*(p2 + bh[2]));
    float hp = hbuf[rd][q];
    float hn = (1.f-z)*nn + z*hp;
    if (sub==0) hbuf[wr][q]=hn;
    __syncthreads();
  }
  if (tid<128){
    int ppos = d? 0 : (NPER-1);
    y[(rowbase+ppos)*256 + d*128 + tid] = (half_t)hbuf[0][tid];
  }
}

// ---------------- head stage 2 ----------------
__global__ __launch_bounds__(256) void head2_kernel(const half_t* __restrict__ hid, const float* __restrict__ W2,
                             const float* __restrict__ b2, float* __restrict__ out){
  int n = (blockIdx.x<<2) + (threadIdx.x>>6);
  int lane = threadIdx.x&63;
  float hv = (float)hid[(size_t)n*64+lane];
  float p0 = hv*W2[lane*2+0];
  float p1 = hv*W2[lane*2+1];
  for (int off=1; off<64; off<<=1){ p0 += __shfl_xor(p0,off); p1 += __shfl_xor(p1,off); }
  if (lane==0){
    out[2*(size_t)n]   = p0 + b2[0];
    out[2*(size_t)n+1] = p1 + b2[1];
  }
}

// ---------------- launch ----------------
extern "C" void kernel_launch(void* const* d_in, const int* in_sizes, int n_in,
                              void* d_out, int out_size, void* d_ws, size_t ws_size,
                              hipStream_t stream) {
  const float* x       = (const float*)d_in[0];
  const float* ea      = (const float*)d_in[1];
  const float* node_W  = (const float*)d_in[2];
  const float* node_b  = (const float*)d_in[3];
  const float* eW      = (const float*)d_in[4];
  const float* eb      = (const float*)d_in[5];
  const float* gat_W   = (const float*)d_in[6];
  const float* gat_We  = (const float*)d_in[7];
  const float* attS    = (const float*)d_in[8];
  const float* attD    = (const float*)d_in[9];
  const float* attE    = (const float*)d_in[10];
  const float* gat_b   = (const float*)d_in[11];
  const float* wih_f   = (const float*)d_in[12];
  const float* whh_f   = (const float*)d_in[13];
  const float* bih_f   = (const float*)d_in[14];
  const float* bhh_f   = (const float*)d_in[15];
  const float* wih_b   = (const float*)d_in[16];
  const float* whh_b   = (const float*)d_in[17];
  const float* bih_b   = (const float*)d_in[18];
  const float* bhh_b   = (const float*)d_in[19];
  const float* head_W1 = (const float*)d_in[20];
  const float* head_b1 = (const float*)d_in[21];
  const float* head_W2 = (const float*)d_in[22];
  const float* head_b2 = (const float*)d_in[23];
  const int*   ei      = (const int*)d_in[24];
  float* out = (float*)d_out;
  char* ws = (char*)d_ws;
  (void)in_sizes; (void)n_in; (void)out_size;

  // ---- adaptive workspace layout with lifetime aliasing ----
  // Persistent small region P, then a shared region holding GAT scratch
  // (dead before gx is written) overlapped with gx (and later hid),
  // then hjk, then y.
  size_t o = 0;
  auto alloc = [&](size_t bytes)->size_t{ size_t r=o; o += (bytes+255)&~(size_t)255; return r; };
  size_t o_vs     = alloc(192*4);
  size_t o_vd     = alloc(192*4);
  size_t o_cc     = alloc(16*4);
  size_t o_biasc  = alloc(768*4);
  size_t o_BcombT = alloc((size_t)768*192*2);
  size_t o_BTgat  = alloc((size_t)3*4096*2);
  size_t o_W1T    = alloc((size_t)64*256*2);
  size_t shared_base = o;

  // GAT scratch inside shared region
  size_t o_deg    = alloc((size_t)NN*4);
  size_t o_cursor = alloc((size_t)NN*4);
  size_t o_aloop  = alloc((size_t)3*NN*4);
  size_t zero_end = o;                      // [shared_base, zero_end) zeroed
  size_t o_rows   = alloc((size_t)NN*4);
  size_t o_bsum   = alloc(512*4);
  size_t o_csr    = alloc((size_t)NE*4);
  size_t o_ae     = alloc((size_t)3*NE*4);
  size_t o_as     = alloc((size_t)NN*4);
  size_t o_ad     = alloc((size_t)NN*4);
  size_t o_exs    = alloc((size_t)NN*4);
  size_t o_den    = alloc((size_t)NN*4);
  size_t o_ex     = alloc((size_t)NE*4);
  size_t o_h      = alloc((size_t)NN*64*2);
  size_t o_xp     = alloc((size_t)NN*64*2);
  size_t gat_end  = o;
  size_t gat_size = gat_end - shared_base;   // ~57 MB

  const size_t GX_FULL  = (size_t)NN*768*2;  // 201 MB
  const size_t GX_HALF  = (size_t)NN*384*2;  // 100 MB
  const size_t HJK_SZ   = (size_t)NN*192*2;  // 48 MB
  const size_t Y_SZ     = (size_t)NN*256*2;  // 67 MB

  auto tail_need = [&](size_t gxsz)->size_t{
    size_t shared = gat_size > gxsz ? gat_size : gxsz;
    return shared_base + shared + HJK_SZ + Y_SZ;
  };
  bool single = tail_need(GX_FULL) <= ws_size;
  size_t gxsz = single ? GX_FULL : GX_HALF;
  size_t shared_sz = gat_size > gxsz ? gat_size : gxsz;
  size_t o_gx  = shared_base;               // aliases GAT scratch (dead by then)
  size_t o_hid = shared_base;               // aliases gx (dead after GRU)
  size_t o_hjk = shared_base + shared_sz;
  size_t o_y   = o_hjk + HJK_SZ;

  int*    deg    = (int*)(ws+o_deg);
  int*    cursor = (int*)(ws+o_cursor);
  float*  aloop  = (float*)(ws+o_aloop);
  int*    rows   = (int*)(ws+o_rows);
  int*    bsum   = (int*)(ws+o_bsum);
  int*    csr    = (int*)(ws+o_csr);
  float*  a_e    = (float*)(ws+o_ae);
  float*  a_s    = (float*)(ws+o_as);
  float*  a_d    = (float*)(ws+o_ad);
  float*  exs    = (float*)(ws+o_exs);
  float*  den    = (float*)(ws+o_den);
  float*  ex     = (float*)(ws+o_ex);
  float*  vs     = (float*)(ws+o_vs);
  float*  vd     = (float*)(ws+o_vd);
  float*  cc     = (float*)(ws+o_cc);
  float*  biasc  = (float*)(ws+o_biasc);
  half_t* h      = (half_t*)(ws+o_h);
  half_t* xp     = (half_t*)(ws+o_xp);
  half_t* hjk    = (half_t*)(ws+o_hjk);
  half_t* BcombT = (half_t*)(ws+o_BcombT);
  half_t* BTgat  = (half_t*)(ws+o_BTgat);
  half_t* W1T    = (half_t*)(ws+o_W1T);
  half_t* gx     = (half_t*)(ws+o_gx);
  half_t* y      = (half_t*)(ws+o_y);
  half_t* hid    = (half_t*)(ws+o_hid);

  hipMemsetAsync(ws+shared_base, 0, zero_end-shared_base, stream);   // deg, cursor, aloop

  const_kernel<<<3,64,0,stream>>>(gat_W, attS, attD, gat_We, attE, eW, eb, vs, vd, cc);
  prep_pack<<<691,256,0,stream>>>(wih_f, wih_b, head_W1, gat_W, bih_f, bih_b, BcombT, W1T, BTgat, biasc);
  embed_kernel<<<32768,256,0,stream>>>(x, node_W, node_b, h);
  edge_pre<<<4096,256,0,stream>>>(ei, ea, cc, a_e, aloop, deg);
  scan1<<<512,256,0,stream>>>(deg, rows, bsum);
  scan2<<<1,512,0,stream>>>(bsum);
  scan3<<<512,256,0,stream>>>(rows, bsum, deg, aloop);
  fill_csr<<<4096,256,0,stream>>>(ei, rows, cursor, csr);

  for (int l=0;l<3;l++){
    gemm_f16<64,false,false><<<dim3(1024,1),256,0,stream>>>(h, BTgat + (size_t)l*4096, nullptr, xp, 64, 64);
    attn_kernel<<<32768,256,0,stream>>>(h, vs + l*64, vd + l*64, aloop + (size_t)l*NN, a_s, a_d, exs);
    hipMemsetAsync(den, 0, (size_t)NN*4, stream);
    edge_soft<<<4096,256,0,stream>>>(ei, a_s, a_d, a_e + (size_t)l*NE, ex, den);
    agg_kernel<<<32768,256,0,stream>>>(ei, rows, deg, csr, ex, exs, den, xp, gat_b + l*64, h, hjk, l);
  }

  if (single){
    gemm_f16<128,true,false><<<dim3(1024,6),256,0,stream>>>(hjk, BcombT, biasc, gx, 192, 768);
    gru_kernel<<<512,512,0,stream>>>(whh_f, whh_b, bhh_f, bhh_b, gx, 768, -1, y);
  } else {
    // forward half
    gemm_f16<128,true,false><<<dim3(1024,3),256,0,stream>>>(hjk, BcombT, biasc, gx, 192, 384);
    gru_kernel<<<256,512,0,stream>>>(whh_f, whh_f, bhh_f, bhh_f, gx, 384, 0, y);
    // backward half (reuse gx region; hjk still alive)
    gemm_f16<128,true,false><<<dim3(1024,3),256,0,stream>>>(hjk, BcombT + (size_t)384*192, biasc + 384, gx, 192, 384);
    gru_kernel<<<256,512,0,stream>>>(whh_b, whh_b, bhh_b, bhh_b, gx, 384, 1, y);
  }

  gemm_f16<64,true,true><<<dim3(1024,1),256,0,stream>>>(y, W1T, head_b1, hid, 256, 64);
  head2_kernel<<<32768,256,0,stream>>>(hid, head_W2, head_b2, out);
}

// Round 3
// 1782.571 us; speedup vs baseline: 1.2433x; 1.2433x over previous
//
#include <hip/hip_runtime.h>
#include <cstdint>
#include <cstddef>

typedef _Float16 half_t;
typedef _Float16 half8 __attribute__((ext_vector_type(8)));
typedef _Float16 half2_t __attribute__((ext_vector_type(2)));
typedef float f32x4 __attribute__((ext_vector_type(4)));

constexpr int NN = 131072;    // nodes
constexpr int NE = 1048576;   // edges
constexpr int NPER = 512;

#define DEVINL __device__ __forceinline__

DEVINL float sigm_(float x){ return 1.f/(1.f+__expf(-x)); }
DEVINL float tanh_(float x){
  x = fminf(15.f, fmaxf(-15.f, x));
  float e = __expf(-2.f*x);
  return (1.f-e)/(1.f+e);
}

union H8 { half8 v8; half2_t h2[4]; };

#if defined(__has_builtin)
#if __has_builtin(__builtin_amdgcn_fdot2)
#define HAVE_FDOT2 1
#endif
#endif

DEVINL float dot2_(half2_t a, half2_t b, float c){
#ifdef HAVE_FDOT2
  return __builtin_amdgcn_fdot2(a, b, c, false);
#else
  return c + (float)a[0]*(float)b[0] + (float)a[1]*(float)b[1];
#endif
}

// ---------------- tiny precompute kernels ----------------

__global__ void const_kernel(const float* __restrict__ gatW, const float* __restrict__ attS,
                             const float* __restrict__ attD, const float* __restrict__ gatWe,
                             const float* __restrict__ attE, const float* __restrict__ eW,
                             const float* __restrict__ eb,
                             float* __restrict__ vs, float* __restrict__ vd, float* __restrict__ cc){
  int l = blockIdx.x, k = threadIdx.x;   // 3 blocks x 64 threads
  const float* Wl = gatW + l*4096;
  const float* Wel = gatWe + l*4096;
  float s1=0.f,s2=0.f,s3=0.f;
  for (int j=0;j<64;j++){
    float as = attS[l*64+j], ad = attD[l*64+j], ae = attE[l*64+j];
    s1 += Wl[k*64+j]*as;
    s2 += Wl[k*64+j]*ad;
    s3 += Wel[k*64+j]*ae;
  }
  vs[l*64+k]=s1; vd[l*64+k]=s2;
  float c0 = eW[k]*s3, c1 = eW[64+k]*s3, cb = eb[k]*s3;
  for (int off=1; off<64; off<<=1){
    c0 += __shfl_xor(c0,off); c1 += __shfl_xor(c1,off); cb += __shfl_xor(cb,off);
  }
  if (k==0){ cc[l]=c0; cc[3+l]=c1; cc[6+l]=cb; }
}

// pack/transpose weights to f16: BcombT[768][192], W1T[64][256], BTgat[3][64][64],
// bias_comb[768], whh16[2][384][128]
__global__ void prep_pack(const float* __restrict__ wih_f, const float* __restrict__ wih_b,
                          const float* __restrict__ head_W1, const float* __restrict__ gat_W,
                          const float* __restrict__ bih_f, const float* __restrict__ bih_b,
                          const float* __restrict__ whh_f, const float* __restrict__ whh_b,
                          half_t* __restrict__ BcombT, half_t* __restrict__ W1T,
                          half_t* __restrict__ BTgat, float* __restrict__ bias_comb,
                          half_t* __restrict__ whh16){
  int gid = blockIdx.x*256 + threadIdx.x;
  if (gid < 147456){                       // BcombT: j<384 from wih_f else wih_b, k-contig
    int j = gid/192, k = gid%192;
    float v = (j<384)? wih_f[j*192+k] : wih_b[(j-384)*192+k];
    BcombT[gid] = (half_t)v;
  } else if (gid < 163840){                // W1T[n][k] = head_W1[k][n]
    int i = gid - 147456;
    int n = i>>8, k = i&255;
    W1T[i] = (half_t)head_W1[k*64+n];
  } else if (gid < 176128){                // BTgat[l][n][k] = gat_W[l][k][n]
    int i = gid - 163840;
    int l = i>>12, r = i&4095;
    int n = r>>6, k = r&63;
    BTgat[i] = (half_t)gat_W[l*4096 + k*64 + n];
  } else if (gid < 176896){
    int i = gid - 176128;
    bias_comb[i] = (i<384)? bih_f[i] : bih_b[i-384];
  } else if (gid < 275200){                // whh16: flat copy f then b (49152 each)
    int i = gid - 176896;
    float v = (i<49152)? whh_f[i] : whh_b[i-49152];
    whh16[i] = (half_t)v;
  }
}

// ---------------- node embedding ----------------
__global__ __launch_bounds__(256) void embed_kernel(const float* __restrict__ x,
                            const float* __restrict__ nW, const float* __restrict__ nb,
                            half_t* __restrict__ h){
  int gid = blockIdx.x*256 + threadIdx.x;
  int n = gid>>6, j = gid&63;
  float v = x[2*n]*nW[j] + x[2*n+1]*nW[64+j] + nb[j];
  h[(size_t)n*64+j] = (half_t)v;
}

// ---------------- edge preprocessing ----------------
__global__ __launch_bounds__(256) void edge_pre(const int* __restrict__ ei, const float* __restrict__ ea,
                         const float* __restrict__ cc,
                         float* __restrict__ a_e, float* __restrict__ aloop, int* __restrict__ deg){
  int e = blockIdx.x*256 + threadIdx.x;
  int dt = ei[NE+e];
  float e0 = ea[2*e], e1 = ea[2*e+1];
  atomicAdd(&deg[dt],1);
  #pragma unroll
  for (int l=0;l<3;l++){
    float v = e0*cc[l] + e1*cc[3+l] + cc[6+l];
    a_e[(size_t)l*NE+e] = v;
    atomicAdd(&aloop[(size_t)l*NN+dt], v);
  }
}

__global__ __launch_bounds__(256) void scan1(const int* __restrict__ deg, int* __restrict__ rowstart,
                      int* __restrict__ bsum){
  __shared__ int sc[256];
  int b=blockIdx.x, t=threadIdx.x, i=b*256+t;
  int v=deg[i]; sc[t]=v; __syncthreads();
  for (int off=1; off<256; off<<=1){
    int tv = (t>=off)? sc[t-off] : 0;
    __syncthreads(); sc[t]+=tv; __syncthreads();
  }
  rowstart[i]=sc[t]-v;
  if (t==255) bsum[b]=sc[255];
}
__global__ void scan2(int* __restrict__ bsum){   // 1 block x 512
  __shared__ int sc[512];
  int t=threadIdx.x; int v=bsum[t]; sc[t]=v; __syncthreads();
  for (int off=1; off<512; off<<=1){
    int tv = (t>=off)? sc[t-off] : 0;
    __syncthreads(); sc[t]+=tv; __syncthreads();
  }
  bsum[t]=sc[t]-v;
}
__global__ __launch_bounds__(256) void scan3(int* __restrict__ rowstart, const int* __restrict__ bsum,
                      const int* __restrict__ deg, float* __restrict__ aloop){
  int b=blockIdx.x, t=threadIdx.x, i=b*256+t;
  rowstart[i]+=bsum[b];
  float dv = (float)max(deg[i],1);
  aloop[i] /= dv; aloop[NN+i] /= dv; aloop[2*(size_t)NN+i] /= dv;
}

// fill CSR: csr_src[slot] = src node, eslot[e] = slot (for per-layer weight scatter)
__global__ __launch_bounds__(256) void fill_csr(const int* __restrict__ ei, const int* __restrict__ rowstart,
                         int* __restrict__ cursor, int* __restrict__ csr_src, int* __restrict__ eslot){
  int e = blockIdx.x*256 + threadIdx.x;
  int dt = ei[NE+e];
  int p = atomicAdd(&cursor[dt],1);
  int slot = rowstart[dt]+p;
  csr_src[slot] = ei[e];
  eslot[e] = slot;
}

// ---------------- GAT per-layer kernels ----------------
__global__ __launch_bounds__(256) void attn_kernel(const half_t* __restrict__ h, const float* __restrict__ vs,
                            const float* __restrict__ vd, const float* __restrict__ aloop,
                            float* __restrict__ a_s, float* __restrict__ a_d, float* __restrict__ exs){
  int n = (blockIdx.x<<2) + (threadIdx.x>>6);
  int lane = threadIdx.x&63;
  float hv = (float)h[(size_t)n*64+lane];
  float ps = hv*vs[lane], pd = hv*vd[lane];
  for (int off=1; off<64; off<<=1){ ps += __shfl_xor(ps,off); pd += __shfl_xor(pd,off); }
  if (lane==0){
    a_s[n]=ps; a_d[n]=pd;
    float al = ps+pd+aloop[n];
    al = al>0.f? al : 0.2f*al;
    exs[n] = __expf(al);
  }
}

__global__ __launch_bounds__(256) void edge_soft(const int* __restrict__ ei, const float* __restrict__ a_s,
                          const float* __restrict__ a_d, const float* __restrict__ a_e,
                          const int* __restrict__ eslot,
                          float* __restrict__ csr_w, float* __restrict__ den){
  int e = blockIdx.x*256 + threadIdx.x;
  int s = ei[e], dt = ei[NE+e];
  float al = a_s[s] + a_d[dt] + a_e[e];
  al = al>0.f? al : 0.2f*al;
  float xv = __expf(al);
  csr_w[eslot[e]] = xv;
  atomicAdd(&den[dt], xv);
}

__global__ __launch_bounds__(256) void agg_kernel(const int* __restrict__ csr_src, const int* __restrict__ rowstart,
                           const int* __restrict__ deg,
                           const float* __restrict__ csr_w, const float* __restrict__ exs,
                           const float* __restrict__ den, const half_t* __restrict__ xp,
                           const float* __restrict__ bias, half_t* __restrict__ hout,
                           half_t* __restrict__ hjk, int l){
  int n = (blockIdx.x<<2) + (threadIdx.x>>6);
  int lane = threadIdx.x&63;
  float acc = exs[n]*(float)xp[(size_t)n*64+lane];
  int st = rowstart[n], cnt = deg[n];
  for (int i=0;i<cnt;i++){
    int src = csr_src[st+i];
    float wv = csr_w[st+i];
    acc += wv*(float)xp[(size_t)src*64+lane];
  }
  float dent = den[n]+exs[n];
  float v = acc/dent + bias[lane];
  v = v>0.f? v : 0.01f*v;
  hout[(size_t)n*64+lane]=(half_t)v;
  hjk[(size_t)n*192 + l*64 + lane]=(half_t)v;
}

// ---------------- f16 MFMA GEMM: C[M,Nout] = A[M,K] @ BT[Nout,K]^T (+bias)(+relu) ----------------
// MAP: A row m maps to hjk row (m>>7)*512 + step0 + (m&127)  (chunked GRU input gemm)
template<int BN, bool BIAS, bool RELU, bool MAP>
__global__ __launch_bounds__(256) void gemm_f16(const half_t* __restrict__ A, const half_t* __restrict__ BT,
                         const float* __restrict__ bias, half_t* __restrict__ C,
                         int K, int Nout, int step0){
  __shared__ half_t As[128*32];
  __shared__ half_t Bs[BN*32];
  const int tid = threadIdx.x;
  const int m0 = blockIdx.x * 128;
  const int n0 = blockIdx.y * BN;
  const int w = tid>>6, lane = tid&63;
  const int lm = lane&15, quad = lane>>4;
  const int wm0 = (BN==128)? (w>>1)*64 : w*32;
  const int wn0 = (BN==128)? (w&1)*64 : 0;
  constexpr int MT = (BN==128)?4:2;
  f32x4 acc[MT][4] = {};
  for (int k0=0; k0<K; k0+=32){
    {
      const int c0 = tid*2;
      #pragma unroll
      for (int u=0;u<2;u++){
        int c=c0+u; int row=c>>2; int off=(c&3)*8;
        int m = m0+row;
        size_t arow = MAP ? ((size_t)(m>>7)*512 + step0 + (m&127)) : (size_t)m;
        *(half8*)(&As[row*32+off]) = *(const half8*)(&A[arow*K + k0 + off]);
      }
      if (BN==128){
        #pragma unroll
        for (int u=0;u<2;u++){
          int c=c0+u; int row=c>>2; int off=(c&3)*8;
          *(half8*)(&Bs[row*32+off]) = *(const half8*)(&BT[(size_t)(n0+row)*K + k0 + off]);
        }
      } else {
        int c=tid; int row=c>>2; int off=(c&3)*8;
        *(half8*)(&Bs[row*32+off]) = *(const half8*)(&BT[(size_t)(n0+row)*K + k0 + off]);
      }
    }
    __syncthreads();
    half8 af[MT], bf[4];
    #pragma unroll
    for (int nt=0;nt<4;nt++) bf[nt] = *(const half8*)(&Bs[(wn0+nt*16+lm)*32 + quad*8]);
    #pragma unroll
    for (int mt=0;mt<MT;mt++) af[mt] = *(const half8*)(&As[(wm0+mt*16+lm)*32 + quad*8]);
    #pragma unroll
    for (int mt=0;mt<MT;mt++)
      #pragma unroll
      for (int nt=0;nt<4;nt++)
        acc[mt][nt] = __builtin_amdgcn_mfma_f32_16x16x32_f16(af[mt], bf[nt], acc[mt][nt], 0,0,0);
    __syncthreads();
  }
  #pragma unroll
  for (int mt=0;mt<MT;mt++)
   #pragma unroll
   for (int nt=0;nt<4;nt++)
    #pragma unroll
    for (int r=0;r<4;r++){
      int m = m0+wm0+mt*16+quad*4+r;
      int n = n0+wn0+nt*16+lm;
      float v = acc[mt][nt][r];
      if (BIAS) v += bias[n];
      if (RELU) v = v>0.f? v : 0.f;
      C[(size_t)m*Nout + n] = (half_t)v;
    }
}

// ---------------- GRU recurrence, chunked (128 steps / launch) ----------------
// 512 blocks (g,d), 512 threads: q=tid>>2 (unit), sub=tid&3 (32-wide k-chunk).
// whh in registers as half2 (fdot2), h state in LDS fp32+fp16, persisted in hstate.
// gxf/gxb: [256][128][384] chunk buffers; forward local j=t, backward j=127-t.
__global__ __launch_bounds__(512,4) void gru_chunk(
    const half_t* __restrict__ whh16, const float* __restrict__ bhh_f, const float* __restrict__ bhh_b,
    const half_t* __restrict__ gxf, const half_t* __restrict__ gxb,
    float* __restrict__ hstate, half_t* __restrict__ y, int c){
  const int bid = blockIdx.x;
  const int g = bid>>1, d = bid&1;
  const half_t* gx = d? gxb : gxf;
  const float* bhh = d? bhh_b : bhh_f;
  const int tid = threadIdx.x;
  const int q = tid>>2, sub = tid&3;
  H8 w[3][4];
  float bh[3];
  #pragma unroll
  for (int i=0;i<3;i++){
    bh[i] = bhh[i*128+q];
    const half_t* wp = whh16 + ((size_t)d*49152) + ((size_t)(i*128+q))*128 + sub*32;
    #pragma unroll
    for (int b=0;b<4;b++) w[i][b].v8 = *(const half8*)(wp + b*8);
  }
  __shared__ float hbuf[2][128];
  __shared__ half_t h16[2][128];
  if (tid<128){
    float hv = hstate[((size_t)d*256+g)*128 + tid];
    hbuf[0][tid]=hv; h16[0][tid]=(half_t)hv;
  }
  __syncthreads();
  // prefetch gx gates for t=0
  {
    int j0 = d? 127 : 0;
    const half_t* gxr = gx + ((size_t)g*128 + j0)*384;
    float gr = (float)gxr[q], gz = (float)gxr[128+q], gn = (float)gxr[256+q];
    for (int t=0;t<128;t++){
      int rd = t&1, wr = rd^1;
      float ngr=0.f, ngz=0.f, ngn=0.f;
      if (t<127){
        int jn = d? (126-t) : (t+1);
        const half_t* gxn = gx + ((size_t)g*128 + jn)*384;
        ngr = (float)gxn[q]; ngz = (float)gxn[128+q]; ngn = (float)gxn[256+q];
      }
      H8 hv[4];
      const half_t* hp16 = &h16[rd][sub*32];
      #pragma unroll
      for (int b=0;b<4;b++) hv[b].v8 = *(const half8*)(hp16 + b*8);
      float p0=0.f,p1=0.f,p2=0.f;
      #pragma unroll
      for (int b=0;b<4;b++)
        #pragma unroll
        for (int u=0;u<4;u++){
          p0 = dot2_(w[0][b].h2[u], hv[b].h2[u], p0);
          p1 = dot2_(w[1][b].h2[u], hv[b].h2[u], p1);
          p2 = dot2_(w[2][b].h2[u], hv[b].h2[u], p2);
        }
      p0 += __shfl_xor(p0,1); p0 += __shfl_xor(p0,2);
      p1 += __shfl_xor(p1,1); p1 += __shfl_xor(p1,2);
      p2 += __shfl_xor(p2,1); p2 += __shfl_xor(p2,2);
      float r = sigm_(gr + p0 + bh[0]);
      float z = sigm_(gz + p1 + bh[1]);
      float nn = tanh_(gn + r*(p2 + bh[2]));
      float hp = hbuf[rd][q];
      float hn = (1.f-z)*nn + z*hp;
      if (sub==0){
        hbuf[wr][q]=hn; h16[wr][q]=(half_t)hn;
        int pos = d? (511 - (c*128 + t)) : (c*128 + t);
        y[((size_t)g*512+pos)*256 + d*128 + q] = (half_t)hn;
      }
      gr=ngr; gz=ngz; gn=ngn;
      __syncthreads();
    }
  }
  if (tid<128) hstate[((size_t)d*256+g)*128 + tid] = hbuf[0][tid];
}

// ---------------- head stage 2 ----------------
__global__ __launch_bounds__(256) void head2_kernel(const half_t* __restrict__ hid, const float* __restrict__ W2,
                             const float* __restrict__ b2, float* __restrict__ out){
  int n = (blockIdx.x<<2) + (threadIdx.x>>6);
  int lane = threadIdx.x&63;
  float hv = (float)hid[(size_t)n*64+lane];
  float p0 = hv*W2[lane*2+0];
  float p1 = hv*W2[lane*2+1];
  for (int off=1; off<64; off<<=1){ p0 += __shfl_xor(p0,off); p1 += __shfl_xor(p1,off); }
  if (lane==0){
    out[2*(size_t)n]   = p0 + b2[0];
    out[2*(size_t)n+1] = p1 + b2[1];
  }
}

// ---------------- launch ----------------
extern "C" void kernel_launch(void* const* d_in, const int* in_sizes, int n_in,
                              void* d_out, int out_size, void* d_ws, size_t ws_size,
                              hipStream_t stream) {
  const float* x       = (const float*)d_in[0];
  const float* ea      = (const float*)d_in[1];
  const float* node_W  = (const float*)d_in[2];
  const float* node_b  = (const float*)d_in[3];
  const float* eW      = (const float*)d_in[4];
  const float* eb      = (const float*)d_in[5];
  const float* gat_W   = (const float*)d_in[6];
  const float* gat_We  = (const float*)d_in[7];
  const float* attS    = (const float*)d_in[8];
  const float* attD    = (const float*)d_in[9];
  const float* attE    = (const float*)d_in[10];
  const float* gat_b   = (const float*)d_in[11];
  const float* wih_f   = (const float*)d_in[12];
  const float* whh_f   = (const float*)d_in[13];
  const float* bih_f   = (const float*)d_in[14];
  const float* bhh_f   = (const float*)d_in[15];
  const float* wih_b   = (const float*)d_in[16];
  const float* whh_b   = (const float*)d_in[17];
  const float* bih_b   = (const float*)d_in[18];
  const float* bhh_b   = (const float*)d_in[19];
  const float* head_W1 = (const float*)d_in[20];
  const float* head_b1 = (const float*)d_in[21];
  const float* head_W2 = (const float*)d_in[22];
  const float* head_b2 = (const float*)d_in[23];
  const int*   ei      = (const int*)d_in[24];
  float* out = (float*)d_out;
  char* ws = (char*)d_ws;
  (void)in_sizes; (void)n_in; (void)out_size; (void)ws_size;

  size_t o = 0;
  auto alloc = [&](size_t bytes)->size_t{ size_t r=o; o += (bytes+255)&~(size_t)255; return r; };
  // persistent region
  size_t o_vs     = alloc(192*4);
  size_t o_vd     = alloc(192*4);
  size_t o_cc     = alloc(16*4);
  size_t o_biasc  = alloc(768*4);
  size_t o_BcombT = alloc((size_t)768*192*2);
  size_t o_BTgat  = alloc((size_t)3*4096*2);
  size_t o_W1T    = alloc((size_t)64*256*2);
  size_t o_whh16  = alloc((size_t)2*49152*2);
  size_t o_hstate = alloc((size_t)2*256*128*4);
  size_t shared_base = o;

  // GAT scratch inside shared region (dead before phase 2)
  size_t o_deg    = alloc((size_t)NN*4);
  size_t o_cursor = alloc((size_t)NN*4);
  size_t o_aloop  = alloc((size_t)3*NN*4);
  size_t zero_end = o;                      // [shared_base, zero_end) zeroed
  size_t o_rows   = alloc((size_t)NN*4);
  size_t o_bsum   = alloc(512*4);
  size_t o_csrs   = alloc((size_t)NE*4);
  size_t o_eslot  = alloc((size_t)NE*4);
  size_t o_csrw   = alloc((size_t)NE*4);
  size_t o_ae     = alloc((size_t)3*NE*4);
  size_t o_as     = alloc((size_t)NN*4);
  size_t o_ad     = alloc((size_t)NN*4);
  size_t o_exs    = alloc((size_t)NN*4);
  size_t o_den    = alloc((size_t)NN*4);
  size_t o_h      = alloc((size_t)NN*64*2);
  size_t o_xp     = alloc((size_t)NN*64*2);
  size_t gat_end  = o;
  size_t gat_size = gat_end - shared_base;

  const size_t GXC    = (size_t)256*128*384*2;   // 25.17 MB per direction chunk
  const size_t HJK_SZ = (size_t)NN*192*2;        // 48 MB
  const size_t Y_SZ   = (size_t)NN*256*2;        // 67 MB
  size_t shared_sz = gat_size > 2*GXC ? gat_size : 2*GXC;
  size_t o_gxf = shared_base;               // aliases GAT scratch (dead)
  size_t o_gxb = shared_base + GXC;
  size_t o_hid = shared_base;               // aliases gx chunks (dead after GRU)
  size_t o_hjk = shared_base + shared_sz;
  size_t o_y   = o_hjk + HJK_SZ;
  (void)Y_SZ;

  int*    deg    = (int*)(ws+o_deg);
  int*    cursor = (int*)(ws+o_cursor);
  float*  aloop  = (float*)(ws+o_aloop);
  int*    rows   = (int*)(ws+o_rows);
  int*    bsum   = (int*)(ws+o_bsum);
  int*    csrs   = (int*)(ws+o_csrs);
  int*    eslot  = (int*)(ws+o_eslot);
  float*  csrw   = (float*)(ws+o_csrw);
  float*  a_e    = (float*)(ws+o_ae);
  float*  a_s    = (float*)(ws+o_as);
  float*  a_d    = (float*)(ws+o_ad);
  float*  exs    = (float*)(ws+o_exs);
  float*  den    = (float*)(ws+o_den);
  float*  vs     = (float*)(ws+o_vs);
  float*  vd     = (float*)(ws+o_vd);
  float*  cc     = (float*)(ws+o_cc);
  float*  biasc  = (float*)(ws+o_biasc);
  half_t* h      = (half_t*)(ws+o_h);
  half_t* xp     = (half_t*)(ws+o_xp);
  half_t* hjk    = (half_t*)(ws+o_hjk);
  half_t* BcombT = (half_t*)(ws+o_BcombT);
  half_t* BTgat  = (half_t*)(ws+o_BTgat);
  half_t* W1T    = (half_t*)(ws+o_W1T);
  half_t* whh16  = (half_t*)(ws+o_whh16);
  float*  hstate = (float*)(ws+o_hstate);
  half_t* gxf    = (half_t*)(ws+o_gxf);
  half_t* gxb    = (half_t*)(ws+o_gxb);
  half_t* y      = (half_t*)(ws+o_y);
  half_t* hid    = (half_t*)(ws+o_hid);

  hipMemsetAsync(ws+shared_base, 0, zero_end-shared_base, stream);   // deg, cursor, aloop
  hipMemsetAsync(ws+o_hstate, 0, (size_t)2*256*128*4, stream);       // GRU h init

  const_kernel<<<3,64,0,stream>>>(gat_W, attS, attD, gat_We, attE, eW, eb, vs, vd, cc);
  prep_pack<<<1075,256,0,stream>>>(wih_f, wih_b, head_W1, gat_W, bih_f, bih_b, whh_f, whh_b,
                                   BcombT, W1T, BTgat, biasc, whh16);
  embed_kernel<<<32768,256,0,stream>>>(x, node_W, node_b, h);
  edge_pre<<<4096,256,0,stream>>>(ei, ea, cc, a_e, aloop, deg);
  scan1<<<512,256,0,stream>>>(deg, rows, bsum);
  scan2<<<1,512,0,stream>>>(bsum);
  scan3<<<512,256,0,stream>>>(rows, bsum, deg, aloop);
  fill_csr<<<4096,256,0,stream>>>(ei, rows, cursor, csrs, eslot);

  for (int l=0;l<3;l++){
    gemm_f16<64,false,false,false><<<dim3(1024,1),256,0,stream>>>(h, BTgat + (size_t)l*4096, nullptr, xp, 64, 64, 0);
    attn_kernel<<<32768,256,0,stream>>>(h, vs + l*64, vd + l*64, aloop + (size_t)l*NN, a_s, a_d, exs);
    hipMemsetAsync(den, 0, (size_t)NN*4, stream);
    edge_soft<<<4096,256,0,stream>>>(ei, a_s, a_d, a_e + (size_t)l*NE, eslot, csrw, den);
    agg_kernel<<<32768,256,0,stream>>>(csrs, rows, deg, csrw, exs, den, xp, gat_b + l*64, h, hjk, l);
  }

  // chunked bidirectional GRU: 4 chunks x 128 steps
  for (int c=0;c<4;c++){
    gemm_f16<128,true,false,true><<<dim3(256,3),256,0,stream>>>(hjk, BcombT, biasc, gxf, 192, 384, c*128);
    gemm_f16<128,true,false,true><<<dim3(256,3),256,0,stream>>>(hjk, BcombT + (size_t)384*192, biasc + 384, gxb, 192, 384, (3-c)*128);
    gru_chunk<<<512,512,0,stream>>>(whh16, bhh_f, bhh_b, gxf, gxb, hstate, y, c);
  }

  gemm_f16<64,true,true,false><<<dim3(1024,1),256,0,stream>>>(y, W1T, head_b1, hid, 256, 64, 0);
  head2_kernel<<<32768,256,0,stream>>>(hid, head_W2, head_b2, out);
}

// Round 4
// 1445.400 us; speedup vs baseline: 1.5333x; 1.2333x over previous
//
#include <hip/hip_runtime.h>
#include <cstdint>
#include <cstddef>

typedef _Float16 half_t;
typedef _Float16 half8 __attribute__((ext_vector_type(8)));
typedef _Float16 half2_t __attribute__((ext_vector_type(2)));
typedef float f32x4 __attribute__((ext_vector_type(4)));

constexpr int NN = 131072;    // nodes
constexpr int NE = 1048576;   // edges
constexpr int NPER = 512;

#define DEVINL __device__ __forceinline__

DEVINL float sigm_(float x){ return 1.f/(1.f+__expf(-x)); }
DEVINL float tanh_(float x){
  x = fminf(15.f, fmaxf(-15.f, x));
  float e = __expf(-2.f*x);
  return (1.f-e)/(1.f+e);
}

union H8 { half8 v8; half2_t h2[4]; };

#if defined(__has_builtin)
#if __has_builtin(__builtin_amdgcn_fdot2)
#define HAVE_FDOT2 1
#endif
#endif

DEVINL float dot2_(half2_t a, half2_t b, float c){
#ifdef HAVE_FDOT2
  return __builtin_amdgcn_fdot2(a, b, c, false);
#else
  return c + (float)a[0]*(float)b[0] + (float)a[1]*(float)b[1];
#endif
}

// ---------------- tiny precompute kernels ----------------

__global__ void const_kernel(const float* __restrict__ gatW, const float* __restrict__ attS,
                             const float* __restrict__ attD, const float* __restrict__ gatWe,
                             const float* __restrict__ attE, const float* __restrict__ eW,
                             const float* __restrict__ eb,
                             float* __restrict__ vs, float* __restrict__ vd, float* __restrict__ cc){
  int l = blockIdx.x, k = threadIdx.x;   // 3 blocks x 64 threads
  const float* Wl = gatW + l*4096;
  const float* Wel = gatWe + l*4096;
  float s1=0.f,s2=0.f,s3=0.f;
  for (int j=0;j<64;j++){
    float as = attS[l*64+j], ad = attD[l*64+j], ae = attE[l*64+j];
    s1 += Wl[k*64+j]*as;
    s2 += Wl[k*64+j]*ad;
    s3 += Wel[k*64+j]*ae;
  }
  vs[l*64+k]=s1; vd[l*64+k]=s2;
  float c0 = eW[k]*s3, c1 = eW[64+k]*s3, cb = eb[k]*s3;
  for (int off=1; off<64; off<<=1){
    c0 += __shfl_xor(c0,off); c1 += __shfl_xor(c1,off); cb += __shfl_xor(cb,off);
  }
  if (k==0){ cc[l]=c0; cc[3+l]=c1; cc[6+l]=cb; }
}

// pack/transpose weights to f16: BcombT[768][192], W1T[64][256], BTgat[3][64][64],
// bias_comb[768], whh16[2][384][128]
__global__ void prep_pack(const float* __restrict__ wih_f, const float* __restrict__ wih_b,
                          const float* __restrict__ head_W1, const float* __restrict__ gat_W,
                          const float* __restrict__ bih_f, const float* __restrict__ bih_b,
                          const float* __restrict__ whh_f, const float* __restrict__ whh_b,
                          half_t* __restrict__ BcombT, half_t* __restrict__ W1T,
                          half_t* __restrict__ BTgat, float* __restrict__ bias_comb,
                          half_t* __restrict__ whh16){
  int gid = blockIdx.x*256 + threadIdx.x;
  if (gid < 147456){                       // BcombT: j<384 from wih_f else wih_b, k-contig
    int j = gid/192, k = gid%192;
    float v = (j<384)? wih_f[j*192+k] : wih_b[(j-384)*192+k];
    BcombT[gid] = (half_t)v;
  } else if (gid < 163840){                // W1T[n][k] = head_W1[k][n]
    int i = gid - 147456;
    int n = i>>8, k = i&255;
    W1T[i] = (half_t)head_W1[k*64+n];
  } else if (gid < 176128){                // BTgat[l][n][k] = gat_W[l][k][n]
    int i = gid - 163840;
    int l = i>>12, r = i&4095;
    int n = r>>6, k = r&63;
    BTgat[i] = (half_t)gat_W[l*4096 + k*64 + n];
  } else if (gid < 176896){
    int i = gid - 176128;
    bias_comb[i] = (i<384)? bih_f[i] : bih_b[i-384];
  } else if (gid < 275200){                // whh16: flat copy f then b (49152 each)
    int i = gid - 176896;
    float v = (i<49152)? whh_f[i] : whh_b[i-49152];
    whh16[i] = (half_t)v;
  }
}

// ---------------- node embedding ----------------
__global__ __launch_bounds__(256) void embed_kernel(const float* __restrict__ x,
                            const float* __restrict__ nW, const float* __restrict__ nb,
                            half_t* __restrict__ h){
  int gid = blockIdx.x*256 + threadIdx.x;
  int n = gid>>6, j = gid&63;
  float v = x[2*n]*nW[j] + x[2*n+1]*nW[64+j] + nb[j];
  h[(size_t)n*64+j] = (half_t)v;
}

// ---------------- edge preprocessing (single atomic pass) ----------------
__global__ __launch_bounds__(256) void deg_count(const int* __restrict__ ei,
                          int* __restrict__ deg, int* __restrict__ tmp){
  int e = blockIdx.x*256 + threadIdx.x;
  int dt = ei[NE+e];
  tmp[e] = atomicAdd(&deg[dt],1);
}

__global__ __launch_bounds__(256) void scan1(const int* __restrict__ deg, int* __restrict__ rowstart,
                      int* __restrict__ bsum){
  __shared__ int sc[256];
  int b=blockIdx.x, t=threadIdx.x, i=b*256+t;
  int v=deg[i]; sc[t]=v; __syncthreads();
  for (int off=1; off<256; off<<=1){
    int tv = (t>=off)? sc[t-off] : 0;
    __syncthreads(); sc[t]+=tv; __syncthreads();
  }
  rowstart[i]=sc[t]-v;
  if (t==255) bsum[b]=sc[255];
}
__global__ void scan2(int* __restrict__ bsum){   // 1 block x 512
  __shared__ int sc[512];
  int t=threadIdx.x; int v=bsum[t]; sc[t]=v; __syncthreads();
  for (int off=1; off<512; off<<=1){
    int tv = (t>=off)? sc[t-off] : 0;
    __syncthreads(); sc[t]+=tv; __syncthreads();
  }
  bsum[t]=sc[t]-v;
}
__global__ __launch_bounds__(256) void scan3(int* __restrict__ rowstart, const int* __restrict__ bsum){
  int b=blockIdx.x, t=threadIdx.x, i=b*256+t;
  rowstart[i]+=bsum[b];
}

// one 16B record per edge slot: {src, ea0, ea1, pad}
__global__ __launch_bounds__(256) void fill2(const int* __restrict__ ei, const float* __restrict__ ea,
                      const int* __restrict__ rowstart, const int* __restrict__ tmp,
                      int4* __restrict__ rec){
  int e = blockIdx.x*256 + threadIdx.x;
  int dt = ei[NE+e];
  int slot = rowstart[dt] + tmp[e];
  int4 r;
  r.x = ei[e];
  r.y = __float_as_int(ea[2*e]);
  r.z = __float_as_int(ea[2*e+1]);
  r.w = 0;
  rec[slot] = r;
}

// per-node mean of incoming edge attrs (for the self-loop 'mean' fill)
__global__ __launch_bounds__(256) void means_kernel(const int* __restrict__ deg, const int* __restrict__ rowstart,
                         const int4* __restrict__ rec, float2* __restrict__ m01){
  int n = blockIdx.x*256 + threadIdx.x;
  int st = rowstart[n], cnt = deg[n];
  float s0=0.f, s1=0.f;
  for (int i=0;i<cnt;i++){
    int4 r = rec[st+i];
    s0 += __int_as_float(r.y);
    s1 += __int_as_float(r.z);
  }
  float inv = 1.f/(float)max(cnt,1);
  float2 m; m.x = s0*inv; m.y = s1*inv;
  m01[n] = m;
}

// ---------------- GAT per-layer kernels ----------------
__global__ __launch_bounds__(256) void attn_kernel(const half_t* __restrict__ in, int lda,
                            const float* __restrict__ vs, const float* __restrict__ vd,
                            float* __restrict__ a_s, float* __restrict__ a_d){
  int n = (blockIdx.x<<2) + (threadIdx.x>>6);
  int lane = threadIdx.x&63;
  float hv = (float)in[(size_t)n*lda+lane];
  float ps = hv*vs[lane], pd = hv*vd[lane];
  for (int off=1; off<64; off<<=1){ ps += __shfl_xor(ps,off); pd += __shfl_xor(pd,off); }
  if (lane==0){ a_s[n]=ps; a_d[n]=pd; }
}

// fused softmax + aggregate: one wave per node, single CSR walk, no atomics
__global__ __launch_bounds__(256) void agg_fused(const int* __restrict__ rowstart, const int* __restrict__ deg,
                          const int4* __restrict__ rec,
                          const float* __restrict__ a_s, const float* __restrict__ a_d,
                          const float2* __restrict__ m01, const float* __restrict__ cc, int l,
                          const half_t* __restrict__ xp, const float* __restrict__ bias,
                          half_t* __restrict__ hjk){
  int n = (blockIdx.x<<2) + (threadIdx.x>>6);
  int lane = threadIdx.x&63;
  float c0=cc[l], c1=cc[3+l], cb=cc[6+l];
  int st = rowstart[n], cnt = deg[n];
  float ad = a_d[n];
  float acc=0.f, den=0.f;
  if (cnt>0){
    int4 r = rec[st];
    for (int i=0;i<cnt;i++){
      int4 rn;
      if (i+1<cnt) rn = rec[st+i+1];
      int src = r.x;
      float al = a_s[src] + ad + __int_as_float(r.y)*c0 + __int_as_float(r.z)*c1 + cb;
      al = al>0.f? al : 0.2f*al;
      float w = __expf(al);
      den += w;
      acc += w*(float)xp[(size_t)src*64+lane];
      r = rn;
    }
  }
  // self-loop (edge feature = mean of incoming, or zero-vector if no incoming)
  float2 m = m01[n];
  float ael = cnt? (m.x*c0 + m.y*c1 + cb) : 0.f;
  float asl = a_s[n] + ad + ael;
  asl = asl>0.f? asl : 0.2f*asl;
  float ws = __expf(asl);
  den += ws;
  acc += ws*(float)xp[(size_t)n*64+lane];
  float v = acc/den + bias[lane];
  v = v>0.f? v : 0.01f*v;
  hjk[(size_t)n*192 + l*64 + lane] = (half_t)v;
}

// ---------------- f16 MFMA GEMM: C[M,Nout] = A[M,K] @ BT[Nout,K]^T (+bias)(+relu) ----------------
// A row stride = lda. MAP: A row m maps to row (m>>7)*512 + step0 + (m&127) (chunked GRU gemm).
template<int BN, bool BIAS, bool RELU, bool MAP>
__global__ __launch_bounds__(256) void gemm_f16(const half_t* __restrict__ A, int lda,
                         const half_t* __restrict__ BT,
                         const float* __restrict__ bias, half_t* __restrict__ C,
                         int K, int Nout, int step0){
  __shared__ half_t As[128*32];
  __shared__ half_t Bs[BN*32];
  const int tid = threadIdx.x;
  const int m0 = blockIdx.x * 128;
  const int n0 = blockIdx.y * BN;
  const int w = tid>>6, lane = tid&63;
  const int lm = lane&15, quad = lane>>4;
  const int wm0 = (BN==128)? (w>>1)*64 : w*32;
  const int wn0 = (BN==128)? (w&1)*64 : 0;
  constexpr int MT = (BN==128)?4:2;
  f32x4 acc[MT][4] = {};
  for (int k0=0; k0<K; k0+=32){
    {
      const int c0 = tid*2;
      #pragma unroll
      for (int u=0;u<2;u++){
        int c=c0+u; int row=c>>2; int off=(c&3)*8;
        int m = m0+row;
        size_t arow = MAP ? ((size_t)(m>>7)*512 + step0 + (m&127)) : (size_t)m;
        *(half8*)(&As[row*32+off]) = *(const half8*)(&A[arow*lda + k0 + off]);
      }
      if (BN==128){
        #pragma unroll
        for (int u=0;u<2;u++){
          int c=c0+u; int row=c>>2; int off=(c&3)*8;
          *(half8*)(&Bs[row*32+off]) = *(const half8*)(&BT[(size_t)(n0+row)*K + k0 + off]);
        }
      } else {
        int c=tid; int row=c>>2; int off=(c&3)*8;
        *(half8*)(&Bs[row*32+off]) = *(const half8*)(&BT[(size_t)(n0+row)*K + k0 + off]);
      }
    }
    __syncthreads();
    half8 af[MT], bf[4];
    #pragma unroll
    for (int nt=0;nt<4;nt++) bf[nt] = *(const half8*)(&Bs[(wn0+nt*16+lm)*32 + quad*8]);
    #pragma unroll
    for (int mt=0;mt<MT;mt++) af[mt] = *(const half8*)(&As[(wm0+mt*16+lm)*32 + quad*8]);
    #pragma unroll
    for (int mt=0;mt<MT;mt++)
      #pragma unroll
      for (int nt=0;nt<4;nt++)
        acc[mt][nt] = __builtin_amdgcn_mfma_f32_16x16x32_f16(af[mt], bf[nt], acc[mt][nt], 0,0,0);
    __syncthreads();
  }
  #pragma unroll
  for (int mt=0;mt<MT;mt++)
   #pragma unroll
   for (int nt=0;nt<4;nt++)
    #pragma unroll
    for (int r=0;r<4;r++){
      int m = m0+wm0+mt*16+quad*4+r;
      int n = n0+wn0+nt*16+lm;
      float v = acc[mt][nt][r];
      if (BIAS) v += bias[n];
      if (RELU) v = v>0.f? v : 0.f;
      C[(size_t)m*Nout + n] = (half_t)v;
    }
}

// ---------------- GRU recurrence, chunked (128 steps / launch) ----------------
__global__ __launch_bounds__(512,4) void gru_chunk(
    const half_t* __restrict__ whh16, const float* __restrict__ bhh_f, const float* __restrict__ bhh_b,
    const half_t* __restrict__ gxf, const half_t* __restrict__ gxb,
    float* __restrict__ hstate, half_t* __restrict__ y, int c){
  const int bid = blockIdx.x;
  const int g = bid>>1, d = bid&1;
  const half_t* gx = d? gxb : gxf;
  const float* bhh = d? bhh_b : bhh_f;
  const int tid = threadIdx.x;
  const int q = tid>>2, sub = tid&3;
  H8 w[3][4];
  float bh[3];
  #pragma unroll
  for (int i=0;i<3;i++){
    bh[i] = bhh[i*128+q];
    const half_t* wp = whh16 + ((size_t)d*49152) + ((size_t)(i*128+q))*128 + sub*32;
    #pragma unroll
    for (int b=0;b<4;b++) w[i][b].v8 = *(const half8*)(wp + b*8);
  }
  __shared__ float hbuf[2][128];
  __shared__ half_t h16[2][128];
  if (tid<128){
    float hv = hstate[((size_t)d*256+g)*128 + tid];
    hbuf[0][tid]=hv; h16[0][tid]=(half_t)hv;
  }
  __syncthreads();
  {
    int j0 = d? 127 : 0;
    const half_t* gxr = gx + ((size_t)g*128 + j0)*384;
    float gr = (float)gxr[q], gz = (float)gxr[128+q], gn = (float)gxr[256+q];
    for (int t=0;t<128;t++){
      int rd = t&1, wr = rd^1;
      float ngr=0.f, ngz=0.f, ngn=0.f;
      if (t<127){
        int jn = d? (126-t) : (t+1);
        const half_t* gxn = gx + ((size_t)g*128 + jn)*384;
        ngr = (float)gxn[q]; ngz = (float)gxn[128+q]; ngn = (float)gxn[256+q];
      }
      H8 hv[4];
      const half_t* hp16 = &h16[rd][sub*32];
      #pragma unroll
      for (int b=0;b<4;b++) hv[b].v8 = *(const half8*)(hp16 + b*8);
      float p0=0.f,p1=0.f,p2=0.f;
      #pragma unroll
      for (int b=0;b<4;b++)
        #pragma unroll
        for (int u=0;u<4;u++){
          p0 = dot2_(w[0][b].h2[u], hv[b].h2[u], p0);
          p1 = dot2_(w[1][b].h2[u], hv[b].h2[u], p1);
          p2 = dot2_(w[2][b].h2[u], hv[b].h2[u], p2);
        }
      p0 += __shfl_xor(p0,1); p0 += __shfl_xor(p0,2);
      p1 += __shfl_xor(p1,1); p1 += __shfl_xor(p1,2);
      p2 += __shfl_xor(p2,1); p2 += __shfl_xor(p2,2);
      float r = sigm_(gr + p0 + bh[0]);
      float z = sigm_(gz + p1 + bh[1]);
      float nn = tanh_(gn + r*(p2 + bh[2]));
      float hp = hbuf[rd][q];
      float hn = (1.f-z)*nn + z*hp;
      if (sub==0){
        hbuf[wr][q]=hn; h16[wr][q]=(half_t)hn;
        int pos = d? (511 - (c*128 + t)) : (c*128 + t);
        y[((size_t)g*512+pos)*256 + d*128 + q] = (half_t)hn;
      }
      gr=ngr; gz=ngz; gn=ngn;
      __syncthreads();
    }
  }
  if (tid<128) hstate[((size_t)d*256+g)*128 + tid] = hbuf[0][tid];
}

// ---------------- head stage 2 ----------------
__global__ __launch_bounds__(256) void head2_kernel(const half_t* __restrict__ hid, const float* __restrict__ W2,
                             const float* __restrict__ b2, float* __restrict__ out){
  int n = (blockIdx.x<<2) + (threadIdx.x>>6);
  int lane = threadIdx.x&63;
  float hv = (float)hid[(size_t)n*64+lane];
  float p0 = hv*W2[lane*2+0];
  float p1 = hv*W2[lane*2+1];
  for (int off=1; off<64; off<<=1){ p0 += __shfl_xor(p0,off); p1 += __shfl_xor(p1,off); }
  if (lane==0){
    out[2*(size_t)n]   = p0 + b2[0];
    out[2*(size_t)n+1] = p1 + b2[1];
  }
}

// ---------------- launch ----------------
extern "C" void kernel_launch(void* const* d_in, const int* in_sizes, int n_in,
                              void* d_out, int out_size, void* d_ws, size_t ws_size,
                              hipStream_t stream) {
  const float* x       = (const float*)d_in[0];
  const float* ea      = (const float*)d_in[1];
  const float* node_W  = (const float*)d_in[2];
  const float* node_b  = (const float*)d_in[3];
  const float* eW      = (const float*)d_in[4];
  const float* eb      = (const float*)d_in[5];
  const float* gat_W   = (const float*)d_in[6];
  const float* gat_We  = (const float*)d_in[7];
  const float* attS    = (const float*)d_in[8];
  const float* attD    = (const float*)d_in[9];
  const float* attE    = (const float*)d_in[10];
  const float* gat_b   = (const float*)d_in[11];
  const float* wih_f   = (const float*)d_in[12];
  const float* whh_f   = (const float*)d_in[13];
  const float* bih_f   = (const float*)d_in[14];
  const float* bhh_f   = (const float*)d_in[15];
  const float* wih_b   = (const float*)d_in[16];
  const float* whh_b   = (const float*)d_in[17];
  const float* bih_b   = (const float*)d_in[18];
  const float* bhh_b   = (const float*)d_in[19];
  const float* head_W1 = (const float*)d_in[20];
  const float* head_b1 = (const float*)d_in[21];
  const float* head_W2 = (const float*)d_in[22];
  const float* head_b2 = (const float*)d_in[23];
  const int*   ei      = (const int*)d_in[24];
  float* out = (float*)d_out;
  char* ws = (char*)d_ws;
  (void)in_sizes; (void)n_in; (void)out_size; (void)ws_size;

  size_t o = 0;
  auto alloc = [&](size_t bytes)->size_t{ size_t r=o; o += (bytes+255)&~(size_t)255; return r; };
  // persistent region
  size_t o_vs     = alloc(192*4);
  size_t o_vd     = alloc(192*4);
  size_t o_cc     = alloc(16*4);
  size_t o_biasc  = alloc(768*4);
  size_t o_BcombT = alloc((size_t)768*192*2);
  size_t o_BTgat  = alloc((size_t)3*4096*2);
  size_t o_W1T    = alloc((size_t)64*256*2);
  size_t o_whh16  = alloc((size_t)2*49152*2);
  size_t o_hstate = alloc((size_t)2*256*128*4);
  size_t shared_base = o;

  // GAT scratch inside shared region (dead before GRU phase)
  size_t o_deg    = alloc((size_t)NN*4);      // zeroed
  size_t zero_end = o;
  size_t o_tmp    = alloc((size_t)NE*4);
  size_t o_rows   = alloc((size_t)NN*4);
  size_t o_bsum   = alloc(512*4);
  size_t o_rec    = alloc((size_t)NE*16);
  size_t o_m01    = alloc((size_t)NN*8);
  size_t o_as     = alloc((size_t)NN*4);
  size_t o_ad     = alloc((size_t)NN*4);
  size_t o_h      = alloc((size_t)NN*64*2);
  size_t o_xp     = alloc((size_t)NN*64*2);
  size_t gat_end  = o;
  size_t gat_size = gat_end - shared_base;

  const size_t GXC    = (size_t)256*128*384*2;   // 25.17 MB per direction chunk
  const size_t HJK_SZ = (size_t)NN*192*2;        // 48 MB
  size_t shared_sz = gat_size > 2*GXC ? gat_size : 2*GXC;
  size_t o_gxf = shared_base;               // aliases GAT scratch (dead)
  size_t o_gxb = shared_base + GXC;
  size_t o_hid = shared_base;               // aliases gx chunks (dead after GRU)
  size_t o_hjk = shared_base + shared_sz;
  size_t o_y   = o_hjk + HJK_SZ;

  int*    deg    = (int*)(ws+o_deg);
  int*    tmp    = (int*)(ws+o_tmp);
  int*    rows   = (int*)(ws+o_rows);
  int*    bsum   = (int*)(ws+o_bsum);
  int4*   rec    = (int4*)(ws+o_rec);
  float2* m01    = (float2*)(ws+o_m01);
  float*  a_s    = (float*)(ws+o_as);
  float*  a_d    = (float*)(ws+o_ad);
  float*  vs     = (float*)(ws+o_vs);
  float*  vd     = (float*)(ws+o_vd);
  float*  cc     = (float*)(ws+o_cc);
  float*  biasc  = (float*)(ws+o_biasc);
  half_t* h      = (half_t*)(ws+o_h);
  half_t* xp     = (half_t*)(ws+o_xp);
  half_t* hjk    = (half_t*)(ws+o_hjk);
  half_t* BcombT = (half_t*)(ws+o_BcombT);
  half_t* BTgat  = (half_t*)(ws+o_BTgat);
  half_t* W1T    = (half_t*)(ws+o_W1T);
  half_t* whh16  = (half_t*)(ws+o_whh16);
  float*  hstate = (float*)(ws+o_hstate);
  half_t* gxf    = (half_t*)(ws+o_gxf);
  half_t* gxb    = (half_t*)(ws+o_gxb);
  half_t* y      = (half_t*)(ws+o_y);
  half_t* hid    = (half_t*)(ws+o_hid);

  hipMemsetAsync(ws+shared_base, 0, zero_end-shared_base, stream);   // deg
  hipMemsetAsync(ws+o_hstate, 0, (size_t)2*256*128*4, stream);       // GRU h init

  const_kernel<<<3,64,0,stream>>>(gat_W, attS, attD, gat_We, attE, eW, eb, vs, vd, cc);
  prep_pack<<<1075,256,0,stream>>>(wih_f, wih_b, head_W1, gat_W, bih_f, bih_b, whh_f, whh_b,
                                   BcombT, W1T, BTgat, biasc, whh16);
  embed_kernel<<<32768,256,0,stream>>>(x, node_W, node_b, h);
  deg_count<<<4096,256,0,stream>>>(ei, deg, tmp);
  scan1<<<512,256,0,stream>>>(deg, rows, bsum);
  scan2<<<1,512,0,stream>>>(bsum);
  scan3<<<512,256,0,stream>>>(rows, bsum);
  fill2<<<4096,256,0,stream>>>(ei, ea, rows, tmp, rec);
  means_kernel<<<512,256,0,stream>>>(deg, rows, rec, m01);

  for (int l=0;l<3;l++){
    const half_t* in = (l==0)? h : (hjk + (size_t)(l-1)*64);
    int lda = (l==0)? 64 : 192;
    gemm_f16<64,false,false,false><<<dim3(1024,1),256,0,stream>>>(in, lda, BTgat + (size_t)l*4096, nullptr, xp, 64, 64, 0);
    attn_kernel<<<32768,256,0,stream>>>(in, lda, vs + l*64, vd + l*64, a_s, a_d);
    agg_fused<<<32768,256,0,stream>>>(rows, deg, rec, a_s, a_d, m01, cc, l, xp, gat_b + l*64, hjk);
  }

  // chunked bidirectional GRU: 4 chunks x 128 steps
  for (int c=0;c<4;c++){
    gemm_f16<128,true,false,true><<<dim3(256,3),256,0,stream>>>(hjk, 192, BcombT, biasc, gxf, 192, 384, c*128);
    gemm_f16<128,true,false,true><<<dim3(256,3),256,0,stream>>>(hjk, 192, BcombT + (size_t)384*192, biasc + 384, gxb, 192, 384, (3-c)*128);
    gru_chunk<<<512,512,0,stream>>>(whh16, bhh_f, bhh_b, gxf, gxb, hstate, y, c);
  }

  gemm_f16<64,true,true,false><<<dim3(1024,1),256,0,stream>>>(y, 256, W1T, head_b1, hid, 256, 64, 0);
  head2_kernel<<<32768,256,0,stream>>>(hid, head_W2, head_b2, out);
}